// Round 18
// baseline (108.876 us; speedup 1.0000x reference)
//
#include <hip/hip_runtime.h>

#define NPTS 262144
#define RES  256
#define PD   32

typedef unsigned short u16;
typedef unsigned int   u32;

typedef __bf16 bf16x8 __attribute__((ext_vector_type(8)));
typedef float  f32x4  __attribute__((ext_vector_type(4)));
typedef u32    u32x2  __attribute__((ext_vector_type(2)));

__device__ __forceinline__ u16 f2bf(float f) {
    return __builtin_bit_cast(u16, (__bf16)f);
}
__device__ __forceinline__ float bf2f(u32 u) {
    return __builtin_bit_cast(float, (u32)(u << 16));
}
__device__ __forceinline__ u32 pk2(float a, float b) {
    return (u32)f2bf(a) | ((u32)f2bf(b) << 16);
}

// ---------------------------------------------------------------------------
// Prep 1: triplanes (3,32,256,256) fp32 -> (3,256,256,32) bf16
// ---------------------------------------------------------------------------
__global__ void k_transpose_planes(const float* __restrict__ tp, u16* __restrict__ dst) {
    const int b  = blockIdx.x;          // 0..767
    const int pl = b >> 8, y = b & 255;
    const int x  = threadIdx.x;         // 0..255
    const float* src = tp + ((size_t)pl * PD * RES + y) * RES + x;
    u32 w[16];
#pragma unroll
    for (int c = 0; c < 16; ++c) {
        const float v0 = src[(size_t)(2 * c)     * (RES * RES)];
        const float v1 = src[(size_t)(2 * c + 1) * (RES * RES)];
        w[c] = (u32)f2bf(v0) | ((u32)f2bf(v1) << 16);
    }
    uint4* d = (uint4*)(dst + (size_t)((pl * RES + y) * RES + x) * PD);
    d[0] = make_uint4(w[0],  w[1],  w[2],  w[3]);
    d[1] = make_uint4(w[4],  w[5],  w[6],  w[7]);
    d[2] = make_uint4(w[8],  w[9],  w[10], w[11]);
    d[3] = make_uint4(w[12], w[13], w[14], w[15]);
}

// ---------------------------------------------------------------------------
// Prep 2: weights -> bf16 (N x K row-major) + W3c transpose (fp32 3x128).
// ---------------------------------------------------------------------------
__global__ void k_prep_weights(const float* __restrict__ dW1, const float* __restrict__ dW2,
                               const float* __restrict__ cW1, const float* __restrict__ cW2,
                               const float* __restrict__ cW3,
                               u16* __restrict__ w1d, u16* __restrict__ w1c,
                               u16* __restrict__ w2d, u16* __restrict__ w2c,
                               float* __restrict__ w3ct) {
    const int tid = blockIdx.x * 256 + threadIdx.x;   // 0..16383
    if (tid < 128 * 32) { const int n = tid >> 5, k = tid & 31; w1d[tid] = f2bf(dW1[k * 128 + n]); }
    if (tid < 128 * 64) { const int n = tid >> 6, k = tid & 63; w1c[tid] = f2bf(k < 59 ? cW1[k * 128 + n] : 0.f); }
    if (tid < 3 * 128) { w3ct[tid] = cW3[(tid & 127) * 3 + (tid >> 7)]; }
    { const int n = tid >> 7, k = tid & 127;
      w2d[tid] = f2bf(dW2[k * 128 + n]);
      w2c[tid] = f2bf(cW2[k * 128 + n]); }
}

// ---------------------------------------------------------------------------
// Fused head kernel. 2048 blocks x 256 threads, 2 sequential 64-pt tiles
// per block. Cross-tile gather prefetch: tile-B's 12 tap loads are issued
// during tile-A's color-GEMM1 phase (same clamped-address math), so tile-B's
// sampling has zero exposed gather latency. Weights recomputed at consume
// (bit-identical). Everything else is the proven r13/r16 structure:
// swapped MFMA, vector sH stores, in-reg W3 dot + shfl(16/32) reduce,
// l4==0 atomics, all b-frag prefetches per tile, r6-verbatim tap masks.
// Loose launch_bounds: aggressive 2nd arg twice caused spill disasters.
// ---------------------------------------------------------------------------
__global__ __launch_bounds__(256) void k_fused(
    const float* __restrict__ pts, const float* __restrict__ vds,
    const u16* __restrict__ planes,
    const u16* __restrict__ gW1d, const u16* __restrict__ gW1c,
    const u16* __restrict__ gW2d, const u16* __restrict__ gW2c,
    const float* __restrict__ gB1d, const float* __restrict__ gB2d,
    const float* __restrict__ gW3d, const float* __restrict__ gB3d,
    const float* __restrict__ gB1c, const float* __restrict__ gB2c,
    const float* __restrict__ gW3ct, const float* __restrict__ gB3c,
    float* __restrict__ out) {
    __shared__ __align__(16) u16 sX[64 * 64];       //  8 KB, 128B rows, swizzled
    __shared__ __align__(16) u16 sH[64 * 128];      // 16 KB, 256B rows, swizzled
    __shared__ float sAcc[2][4 * 64];               //  2 KB (one per tile)

    const int t    = threadIdx.x;
    const int lane = t & 63;
    const int wc   = t >> 6;          // wave = n-column group (0..3)
    const int l15  = lane & 15;
    const int l4   = lane >> 4;
    const int kb   = l4 * 16;         // byte offset of lane's k-slice in a 64B k-step
    const f32x4 FZ = {0.f, 0.f, 0.f, 0.f};

    sAcc[0][t] = 0.f;
    sAcc[1][t] = 0.f;

    // ---- prefetch: density GEMM1 b-frags (tile-invariant) ----
    bf16x8 b1d[2];
#pragma unroll
    for (int nl = 0; nl < 2; ++nl) {
        const int n = wc * 32 + nl * 16 + l15;
        b1d[nl] = *(const bf16x8*)(gW1d + n * 32 + l4 * 8);
    }

    uint4 tvp[12];   // cross-tile tap prefetch (filled in tile 0's color G1)

#pragma unroll
    for (int tile = 0; tile < 2; ++tile) {
        const int pbase = blockIdx.x * 128 + tile * 64;
        float* sAccT = sAcc[tile];

        // ---- sampling + view embedding -> sX ----
        {
            const int p = t >> 2, q = t & 3;       // 4 threads/point
            const int pg = pbase + p;
            const int sw = (p & 7) << 4;
            const float pu = pts[pg], pv = pts[NPTS + pg], pw = pts[2 * NPTS + pg];

            uint4 tv[12];
            float wts[12];

            // pass 1: weights (+ loads for tile 0; tile 1 uses prefetched)
#pragma unroll
            for (int pl = 0; pl < 3; ++pl) {
                const float gx = (pl == 0) ? pv : pu;
                const float gy = (pl == 2) ? pv : pw;
                const float px = (gx + 1.f) * 127.5f;
                const float py = (gy + 1.f) * 127.5f;
                const float x0 = floorf(px), y0 = floorf(py);
                const float fx = px - x0, fy = py - y0;
                const int ix = (int)x0, iy = (int)y0;
                const u16* pb = planes + (size_t)pl * (RES * RES * PD) + q * 8;
#pragma unroll
                for (int dy = 0; dy < 2; ++dy) {
#pragma unroll
                    for (int dx = 0; dx < 2; ++dx) {
                        const int i = pl * 4 + dy * 2 + dx;
                        const int xi = ix + dx, yi = iy + dy;
                        float wt = (dx ? fx : 1.f - fx) * (dy ? fy : 1.f - fy);
                        if (xi < 0 || xi > RES - 1 || yi < 0 || yi > RES - 1) wt = 0.f;
                        const int xc = xi < 0 ? 0 : (xi > RES - 1 ? RES - 1 : xi);
                        const int yc = yi < 0 ? 0 : (yi > RES - 1 ? RES - 1 : yi);
                        wts[i] = wt;
                        if (tile == 0)
                            tv[i] = *(const uint4*)(pb + ((size_t)(yc * RES + xc) << 5));
                        else
                            tv[i] = tvp[i];
                    }
                }
            }

            // pass 2: consume in r6-identical order
            float facc[8] = {0.f, 0.f, 0.f, 0.f, 0.f, 0.f, 0.f, 0.f};
#pragma unroll
            for (int i = 0; i < 12; ++i) {
                const float wt = wts[i];
                const uint4 v = tv[i];
                facc[0] += wt * bf2f(v.x & 0xffffu);
                facc[1] += wt * bf2f(v.x >> 16);
                facc[2] += wt * bf2f(v.y & 0xffffu);
                facc[3] += wt * bf2f(v.y >> 16);
                facc[4] += wt * bf2f(v.z & 0xffffu);
                facc[5] += wt * bf2f(v.z >> 16);
                facc[6] += wt * bf2f(v.w & 0xffffu);
                facc[7] += wt * bf2f(v.w >> 16);
            }
            {
                u32 wp[4];
#pragma unroll
                for (int i = 0; i < 4; ++i) wp[i] = pk2(facc[2 * i], facc[2 * i + 1]);
                *(uint4*)((char*)sX + p * 128 + ((q * 16) ^ sw)) =
                    make_uint4(wp[0], wp[1], wp[2], wp[3]);
            }

            // view embedding -> X cols 32..63 (59..63 zero)
            if (q == 1 || q == 2) {
                const float d0 = vds[pg], d1 = vds[NPTS + pg], d2 = vds[2 * NPTS + pg];
                float e[16];
                if (q == 1) {
                    e[0] = d0; e[1] = d1; e[2] = d2;
#pragma unroll
                    for (int f = 0; f < 4; ++f) {
                        const float fr = (float)(1 << f);
                        e[3 + f * 3 + 0] = __sinf(d0 * fr);
                        e[3 + f * 3 + 1] = __sinf(d1 * fr);
                        e[3 + f * 3 + 2] = __sinf(d2 * fr);
                    }
                    e[15] = __cosf(d0);
                } else {
                    e[0] = __cosf(d1); e[1] = __cosf(d2);
#pragma unroll
                    for (int f = 1; f < 4; ++f) {
                        const float fr = (float)(1 << f);
                        e[2 + (f - 1) * 3 + 0] = __cosf(d0 * fr);
                        e[2 + (f - 1) * 3 + 1] = __cosf(d1 * fr);
                        e[2 + (f - 1) * 3 + 2] = __cosf(d2 * fr);
                    }
#pragma unroll
                    for (int i = 11; i < 16; ++i) e[i] = 0.f;
                }
                const int base = 64 + (q - 1) * 32;
#pragma unroll
                for (int g = 0; g < 2; ++g) {
                    const u32 a0 = pk2(e[8 * g + 0], e[8 * g + 1]);
                    const u32 a1 = pk2(e[8 * g + 2], e[8 * g + 3]);
                    const u32 a2 = pk2(e[8 * g + 4], e[8 * g + 5]);
                    const u32 a3 = pk2(e[8 * g + 6], e[8 * g + 7]);
                    *(uint4*)((char*)sX + p * 128 + ((base + g * 16) ^ sw)) =
                        make_uint4(a0, a1, a2, a3);
                }
            }
        }

        // ---- prefetch: density GEMM2 b-frags kk=0,1 ----
        bf16x8 b2dp[4];
#pragma unroll
        for (int nl = 0; nl < 2; ++nl)
#pragma unroll
            for (int kk = 0; kk < 2; ++kk) {
                const int n = wc * 32 + nl * 16 + l15;
                b2dp[nl * 2 + kk] = *(const bf16x8*)(gW2d + n * 128 + kk * 32 + l4 * 8);
            }
        __syncthreads();                              // barrier 1

        bf16x8 b1cp[4];

        // ================= DENSITY: GEMM1 (K=32), swapped =================
        {
            f32x4 acc[4][2];
            bf16x8 a[4];
#pragma unroll
            for (int mt = 0; mt < 4; ++mt) {
                const int m = mt * 16 + l15;
                a[mt] = *(const bf16x8*)((const char*)sX + m * 128 + (kb ^ ((m & 7) << 4)));
#pragma unroll
                for (int nl = 0; nl < 2; ++nl) acc[mt][nl] = FZ;
            }
#pragma unroll
            for (int nl = 0; nl < 2; ++nl)
#pragma unroll
                for (int mt = 0; mt < 4; ++mt)
                    acc[mt][nl] = __builtin_amdgcn_mfma_f32_16x16x32_bf16(b1d[nl], a[mt], acc[mt][nl], 0, 0, 0);

            // prefetch color GEMM1 b-frags
#pragma unroll
            for (int nl = 0; nl < 2; ++nl)
#pragma unroll
                for (int kk = 0; kk < 2; ++kk) {
                    const int n = wc * 32 + nl * 16 + l15;
                    b1cp[nl * 2 + kk] = *(const bf16x8*)(gW1c + n * 64 + kk * 32 + l4 * 8);
                }

#pragma unroll
            for (int nl = 0; nl < 2; ++nl) {
                const int n0 = wc * 32 + nl * 16 + l4 * 4;
                const f32x4 bv = *(const f32x4*)(gB1d + n0);
#pragma unroll
                for (int mt = 0; mt < 4; ++mt) {
                    const int m = mt * 16 + l15;
                    const float h0 = fmaxf(acc[mt][nl][0] + bv[0], 0.f);
                    const float h1 = fmaxf(acc[mt][nl][1] + bv[1], 0.f);
                    const float h2 = fmaxf(acc[mt][nl][2] + bv[2], 0.f);
                    const float h3 = fmaxf(acc[mt][nl][3] + bv[3], 0.f);
                    *(u32x2*)((char*)sH + m * 256 + ((n0 * 2) ^ ((m & 7) << 4))) =
                        u32x2{pk2(h0, h1), pk2(h2, h3)};
                }
            }
        }
        __syncthreads();                              // barrier 2

        bf16x8 b2cp[4];

        // ================= DENSITY: GEMM2 (K=128), swapped + W3 dot =================
        {
            f32x4 bv[2], wv[2];
#pragma unroll
            for (int nl = 0; nl < 2; ++nl) {
                const int n0 = wc * 32 + nl * 16 + l4 * 4;
                bv[nl] = *(const f32x4*)(gB2d + n0);
                wv[nl] = *(const f32x4*)(gW3d + n0);
            }

            f32x4 acc[4][2];
#pragma unroll
            for (int mt = 0; mt < 4; ++mt)
#pragma unroll
                for (int nl = 0; nl < 2; ++nl) acc[mt][nl] = FZ;
#pragma unroll
            for (int kk = 0; kk < 4; ++kk) {
                bf16x8 a[4];
#pragma unroll
                for (int mt = 0; mt < 4; ++mt) {
                    const int m = mt * 16 + l15;
                    a[mt] = *(const bf16x8*)((const char*)sH + m * 256 + ((kk * 64 + kb) ^ ((m & 7) << 4)));
                }
#pragma unroll
                for (int nl = 0; nl < 2; ++nl) {
                    const int n = wc * 32 + nl * 16 + l15;
                    const bf16x8 b = (kk < 2) ? b2dp[nl * 2 + kk]
                                              : *(const bf16x8*)(gW2d + n * 128 + kk * 32 + l4 * 8);
#pragma unroll
                    for (int mt = 0; mt < 4; ++mt)
                        acc[mt][nl] = __builtin_amdgcn_mfma_f32_16x16x32_bf16(b, a[mt], acc[mt][nl], 0, 0, 0);
                }
            }

            // prefetch color GEMM2 kk=0,1
#pragma unroll
            for (int nl = 0; nl < 2; ++nl)
#pragma unroll
                for (int kk = 0; kk < 2; ++kk) {
                    const int n = wc * 32 + nl * 16 + l15;
                    b2cp[nl * 2 + kk] = *(const bf16x8*)(gW2c + n * 128 + kk * 32 + l4 * 8);
                }

#pragma unroll
            for (int mt = 0; mt < 4; ++mt) {
                float s = 0.f;
#pragma unroll
                for (int nl = 0; nl < 2; ++nl)
#pragma unroll
                    for (int r = 0; r < 4; ++r) {
                        const float h = fmaxf(acc[mt][nl][r] + bv[nl][r], 0.f);
                        s += h * wv[nl][r];
                    }
                s += __shfl_xor(s, 16);
                s += __shfl_xor(s, 32);
                if (l4 == 0)
                    atomicAdd(&sAccT[0 * 64 + mt * 16 + l15], s);
            }
        }
        __syncthreads();                              // barrier 3

        // ================= COLOR: GEMM1 (K=64), swapped =================
        {
            // cross-tile tap prefetch for tile 1 (issued here, consumed in
            // tile 1's sampling; addresses identical to its pass-1 math)
            if (tile == 0) {
                const int p2 = t >> 2, q2 = t & 3;
                const int pg2 = blockIdx.x * 128 + 64 + p2;
                const float pu2 = pts[pg2], pv2 = pts[NPTS + pg2], pw2 = pts[2 * NPTS + pg2];
#pragma unroll
                for (int pl = 0; pl < 3; ++pl) {
                    const float gx = (pl == 0) ? pv2 : pu2;
                    const float gy = (pl == 2) ? pv2 : pw2;
                    const float px = (gx + 1.f) * 127.5f;
                    const float py = (gy + 1.f) * 127.5f;
                    const float x0 = floorf(px), y0 = floorf(py);
                    const int ix = (int)x0, iy = (int)y0;
                    const u16* pb = planes + (size_t)pl * (RES * RES * PD) + q2 * 8;
#pragma unroll
                    for (int dy = 0; dy < 2; ++dy) {
#pragma unroll
                        for (int dx = 0; dx < 2; ++dx) {
                            const int i = pl * 4 + dy * 2 + dx;
                            const int xi = ix + dx, yi = iy + dy;
                            const int xc = xi < 0 ? 0 : (xi > RES - 1 ? RES - 1 : xi);
                            const int yc = yi < 0 ? 0 : (yi > RES - 1 ? RES - 1 : yi);
                            tvp[i] = *(const uint4*)(pb + ((size_t)(yc * RES + xc) << 5));
                        }
                    }
                }
            }

            f32x4 acc[4][2];
#pragma unroll
            for (int mt = 0; mt < 4; ++mt)
#pragma unroll
                for (int nl = 0; nl < 2; ++nl) acc[mt][nl] = FZ;
#pragma unroll
            for (int kk = 0; kk < 2; ++kk) {
                bf16x8 a[4];
#pragma unroll
                for (int mt = 0; mt < 4; ++mt) {
                    const int m = mt * 16 + l15;
                    a[mt] = *(const bf16x8*)((const char*)sX + m * 128 + ((kk * 64 + kb) ^ ((m & 7) << 4)));
                }
#pragma unroll
                for (int nl = 0; nl < 2; ++nl)
#pragma unroll
                    for (int mt = 0; mt < 4; ++mt)
                        acc[mt][nl] = __builtin_amdgcn_mfma_f32_16x16x32_bf16(b1cp[nl * 2 + kk], a[mt], acc[mt][nl], 0, 0, 0);
            }
#pragma unroll
            for (int nl = 0; nl < 2; ++nl) {
                const int n0 = wc * 32 + nl * 16 + l4 * 4;
                const f32x4 bv = *(const f32x4*)(gB1c + n0);
#pragma unroll
                for (int mt = 0; mt < 4; ++mt) {
                    const int m = mt * 16 + l15;
                    const float h0 = fmaxf(acc[mt][nl][0] + bv[0], 0.f);
                    const float h1 = fmaxf(acc[mt][nl][1] + bv[1], 0.f);
                    const float h2 = fmaxf(acc[mt][nl][2] + bv[2], 0.f);
                    const float h3 = fmaxf(acc[mt][nl][3] + bv[3], 0.f);
                    *(u32x2*)((char*)sH + m * 256 + ((n0 * 2) ^ ((m & 7) << 4))) =
                        u32x2{pk2(h0, h1), pk2(h2, h3)};
                }
            }
        }
        __syncthreads();                              // barrier 4

        // ================= COLOR: GEMM2 (K=128), swapped + W3 dots =================
        {
            f32x4 bv[2], w0v[2], w1v[2], w2v[2];
#pragma unroll
            for (int nl = 0; nl < 2; ++nl) {
                const int n0 = wc * 32 + nl * 16 + l4 * 4;
                bv[nl]  = *(const f32x4*)(gB2c + n0);
                w0v[nl] = *(const f32x4*)(gW3ct + 0 * 128 + n0);
                w1v[nl] = *(const f32x4*)(gW3ct + 1 * 128 + n0);
                w2v[nl] = *(const f32x4*)(gW3ct + 2 * 128 + n0);
            }

            f32x4 acc[4][2];
#pragma unroll
            for (int mt = 0; mt < 4; ++mt)
#pragma unroll
                for (int nl = 0; nl < 2; ++nl) acc[mt][nl] = FZ;
#pragma unroll
            for (int kk = 0; kk < 4; ++kk) {
                bf16x8 a[4];
#pragma unroll
                for (int mt = 0; mt < 4; ++mt) {
                    const int m = mt * 16 + l15;
                    a[mt] = *(const bf16x8*)((const char*)sH + m * 256 + ((kk * 64 + kb) ^ ((m & 7) << 4)));
                }
#pragma unroll
                for (int nl = 0; nl < 2; ++nl) {
                    const int n = wc * 32 + nl * 16 + l15;
                    const bf16x8 b = (kk < 2) ? b2cp[nl * 2 + kk]
                                              : *(const bf16x8*)(gW2c + n * 128 + kk * 32 + l4 * 8);
#pragma unroll
                    for (int mt = 0; mt < 4; ++mt)
                        acc[mt][nl] = __builtin_amdgcn_mfma_f32_16x16x32_bf16(b, a[mt], acc[mt][nl], 0, 0, 0);
                }
            }

#pragma unroll
            for (int mt = 0; mt < 4; ++mt) {
                float s0 = 0.f, s1 = 0.f, s2 = 0.f;
#pragma unroll
                for (int nl = 0; nl < 2; ++nl)
#pragma unroll
                    for (int r = 0; r < 4; ++r) {
                        const float h = fmaxf(acc[mt][nl][r] + bv[nl][r], 0.f);
                        s0 += h * w0v[nl][r];
                        s1 += h * w1v[nl][r];
                        s2 += h * w2v[nl][r];
                    }
                s0 += __shfl_xor(s0, 16); s0 += __shfl_xor(s0, 32);
                s1 += __shfl_xor(s1, 16); s1 += __shfl_xor(s1, 32);
                s2 += __shfl_xor(s2, 16); s2 += __shfl_xor(s2, 32);
                if (l4 == 0) {
                    atomicAdd(&sAccT[1 * 64 + mt * 16 + l15], s0);
                    atomicAdd(&sAccT[2 * 64 + mt * 16 + l15], s1);
                    atomicAdd(&sAccT[3 * 64 + mt * 16 + l15], s2);
                }
            }
        }
        __syncthreads();                              // barrier 5

        // ---- write out (1,4,N) for this tile ----
        {
            const int ch = t >> 6, row = t & 63;
            const float bias = (ch == 0) ? gB3d[0] : gB3c[ch - 1];
            out[(size_t)ch * NPTS + pbase + row] = sAccT[ch * 64 + row] + bias;
        }
    }
}

// ---------------------------------------------------------------------------
extern "C" void kernel_launch(void* const* d_in, const int* in_sizes, int n_in,
                              void* d_out, int out_size, void* d_ws, size_t ws_size,
                              hipStream_t stream) {
    (void)in_sizes; (void)n_in; (void)out_size; (void)ws_size;
    const float* pts = (const float*)d_in[0];
    const float* vds = (const float*)d_in[1];
    const float* tp  = (const float*)d_in[2];
    const float* dW1 = (const float*)d_in[3];
    const float* dB1 = (const float*)d_in[4];
    const float* dW2 = (const float*)d_in[5];
    const float* dB2 = (const float*)d_in[6];
    const float* dW3 = (const float*)d_in[7];
    const float* dB3 = (const float*)d_in[8];
    const float* cW1 = (const float*)d_in[9];
    const float* cB1 = (const float*)d_in[10];
    const float* cW2 = (const float*)d_in[11];
    const float* cB2 = (const float*)d_in[12];
    const float* cW3 = (const float*)d_in[13];
    const float* cB3 = (const float*)d_in[14];
    float* out = (float*)d_out;

    u16* planes_t = (u16*)d_ws;                          // 12 MB
    u16* w1d = planes_t + (size_t)3 * RES * RES * PD;
    u16* w1c = w1d + 128 * 32;
    u16* w2d = w1c + 128 * 64;
    u16* w2c = w2d + 128 * 128;
    float* w3ct = (float*)(w2c + 128 * 128);             // 3*128 fp32

    k_transpose_planes<<<3 * RES, 256, 0, stream>>>(tp, planes_t);
    k_prep_weights<<<64, 256, 0, stream>>>(dW1, dW2, cW1, cW2, cW3,
                                           w1d, w1c, w2d, w2c, w3ct);
    k_fused<<<NPTS / 128, 256, 0, stream>>>(pts, vds, planes_t,
                                            w1d, w1c, w2d, w2c,
                                            dB1, dB2, dW3, dB3,
                                            cB1, cB2, w3ct, cB3,
                                            out);
}

// Round 19
// 89.044 us; speedup vs baseline: 1.2227x; 1.2227x over previous
//
#include <hip/hip_runtime.h>

#define NPTS 262144
#define RES  256
#define PD   32

typedef unsigned short u16;
typedef unsigned int   u32;

typedef __bf16 bf16x8 __attribute__((ext_vector_type(8)));
typedef float  f32x4  __attribute__((ext_vector_type(4)));
typedef u32    u32x2  __attribute__((ext_vector_type(2)));

__device__ __forceinline__ u16 f2bf(float f) {
    return __builtin_bit_cast(u16, (__bf16)f);
}
__device__ __forceinline__ float bf2f(u32 u) {
    return __builtin_bit_cast(float, (u32)(u << 16));
}
__device__ __forceinline__ u32 pk2(float a, float b) {
    return (u32)f2bf(a) | ((u32)f2bf(b) << 16);
}

// ---------------------------------------------------------------------------
// Prep 1: triplanes (3,32,256,256) fp32 -> (3,256,256,32) bf16
// ---------------------------------------------------------------------------
__global__ void k_transpose_planes(const float* __restrict__ tp, u16* __restrict__ dst) {
    const int b  = blockIdx.x;          // 0..767
    const int pl = b >> 8, y = b & 255;
    const int x  = threadIdx.x;         // 0..255
    const float* src = tp + ((size_t)pl * PD * RES + y) * RES + x;
    u32 w[16];
#pragma unroll
    for (int c = 0; c < 16; ++c) {
        const float v0 = src[(size_t)(2 * c)     * (RES * RES)];
        const float v1 = src[(size_t)(2 * c + 1) * (RES * RES)];
        w[c] = (u32)f2bf(v0) | ((u32)f2bf(v1) << 16);
    }
    uint4* d = (uint4*)(dst + (size_t)((pl * RES + y) * RES + x) * PD);
    d[0] = make_uint4(w[0],  w[1],  w[2],  w[3]);
    d[1] = make_uint4(w[4],  w[5],  w[6],  w[7]);
    d[2] = make_uint4(w[8],  w[9],  w[10], w[11]);
    d[3] = make_uint4(w[12], w[13], w[14], w[15]);
}

// ---------------------------------------------------------------------------
// Prep 2: weights -> bf16 (N x K row-major) + W3c transpose (fp32 3x128).
// ---------------------------------------------------------------------------
__global__ void k_prep_weights(const float* __restrict__ dW1, const float* __restrict__ dW2,
                               const float* __restrict__ cW1, const float* __restrict__ cW2,
                               const float* __restrict__ cW3,
                               u16* __restrict__ w1d, u16* __restrict__ w1c,
                               u16* __restrict__ w2d, u16* __restrict__ w2c,
                               float* __restrict__ w3ct) {
    const int tid = blockIdx.x * 256 + threadIdx.x;   // 0..16383
    if (tid < 128 * 32) { const int n = tid >> 5, k = tid & 31; w1d[tid] = f2bf(dW1[k * 128 + n]); }
    if (tid < 128 * 64) { const int n = tid >> 6, k = tid & 63; w1c[tid] = f2bf(k < 59 ? cW1[k * 128 + n] : 0.f); }
    if (tid < 3 * 128) { w3ct[tid] = cW3[(tid & 127) * 3 + (tid >> 7)]; }
    { const int n = tid >> 7, k = tid & 127;
      w2d[tid] = f2bf(dW2[k * 128 + n]);
      w2c[tid] = f2bf(cW2[k * 128 + n]); }
}

// ---------------------------------------------------------------------------
// Fused head kernel. 4096 blocks x 256 threads, TILE = 64 points/block.
// BEST CONFIG (r16, 88.78us total): two-pass r6-verbatim sampling, swapped
// MFMA operands, vector sH stores, in-reg W3 dot + shfl(16/32) cross-l4
// reduce, l4==0 atomics, all b-frag prefetches.
// Session ledger of falsified alternatives (do not retry):
//  - launch_bounds (512,6)/(256,5): allocator clamp -> 254MB spill traffic
//  - 42KB-LDS phase merge: occupancy loss > barrier savings (r9)
//  - zero-barrier per-wave form: 4x weight traffic, serial chains (r4)
//  - split sample/MLP kernels: lost overlap + X round-trip (r7)
//  - dropping b2* prefetches: +4us (r14)
//  - no-mask sampling rewrite: WRONG twice (r8/r11) -- keep masked form
//  - packed f32x2 FMA / 2-pass load hoist: null (r16/r17)
//  - cross-tile gather prefetch: +48 VGPR -> occupancy loss, +20us (r18)
// ---------------------------------------------------------------------------
__global__ __launch_bounds__(256) void k_fused(
    const float* __restrict__ pts, const float* __restrict__ vds,
    const u16* __restrict__ planes,
    const u16* __restrict__ gW1d, const u16* __restrict__ gW1c,
    const u16* __restrict__ gW2d, const u16* __restrict__ gW2c,
    const float* __restrict__ gB1d, const float* __restrict__ gB2d,
    const float* __restrict__ gW3d, const float* __restrict__ gB3d,
    const float* __restrict__ gB1c, const float* __restrict__ gB2c,
    const float* __restrict__ gW3ct, const float* __restrict__ gB3c,
    float* __restrict__ out) {
    __shared__ __align__(16) u16 sX[64 * 64];       //  8 KB, 128B rows, swizzled
    __shared__ __align__(16) u16 sH[64 * 128];      // 16 KB, 256B rows, swizzled
    __shared__ float sAcc[4 * 64];                  //  1 KB

    const int t    = threadIdx.x;
    const int lane = t & 63;
    const int wc   = t >> 6;          // wave = n-column group (0..3)
    const int l15  = lane & 15;
    const int l4   = lane >> 4;
    const int kb   = l4 * 16;         // byte offset of lane's k-slice in a 64B k-step
    const int pbase = blockIdx.x * 64;
    const f32x4 FZ = {0.f, 0.f, 0.f, 0.f};

    sAcc[t] = 0.f;

    // ---- prefetch: density GEMM1 b-frags (in flight during sampling) ----
    bf16x8 b1d[2];
#pragma unroll
    for (int nl = 0; nl < 2; ++nl) {
        const int n = wc * 32 + nl * 16 + l15;
        b1d[nl] = *(const bf16x8*)(gW1d + n * 32 + l4 * 8);
    }

    // ---- phase 1: bilinear triplane sampling + view embedding -> sX ----
    {
        const int p = t >> 2, q = t & 3;       // 4 threads/point
        const int pg = pbase + p;
        const int sw = (p & 7) << 4;
        const float pu = pts[pg], pv = pts[NPTS + pg], pw = pts[2 * NPTS + pg];

        uint4 tv[12];
        float wts[12];

        // pass 1: weights + issue all 12 loads (r6-verbatim masks/clamps)
#pragma unroll
        for (int pl = 0; pl < 3; ++pl) {
            const float gx = (pl == 0) ? pv : pu;
            const float gy = (pl == 2) ? pv : pw;
            const float px = (gx + 1.f) * 127.5f;
            const float py = (gy + 1.f) * 127.5f;
            const float x0 = floorf(px), y0 = floorf(py);
            const float fx = px - x0, fy = py - y0;
            const int ix = (int)x0, iy = (int)y0;
            const u16* pb = planes + (size_t)pl * (RES * RES * PD) + q * 8;
#pragma unroll
            for (int dy = 0; dy < 2; ++dy) {
#pragma unroll
                for (int dx = 0; dx < 2; ++dx) {
                    const int i = pl * 4 + dy * 2 + dx;
                    const int xi = ix + dx, yi = iy + dy;
                    float wt = (dx ? fx : 1.f - fx) * (dy ? fy : 1.f - fy);
                    if (xi < 0 || xi > RES - 1 || yi < 0 || yi > RES - 1) wt = 0.f;
                    const int xc = xi < 0 ? 0 : (xi > RES - 1 ? RES - 1 : xi);
                    const int yc = yi < 0 ? 0 : (yi > RES - 1 ? RES - 1 : yi);
                    wts[i] = wt;
                    tv[i] = *(const uint4*)(pb + ((size_t)(yc * RES + xc) << 5));
                }
            }
        }

        // pass 2: consume in identical order
        float facc[8] = {0.f, 0.f, 0.f, 0.f, 0.f, 0.f, 0.f, 0.f};
#pragma unroll
        for (int i = 0; i < 12; ++i) {
            const float wt = wts[i];
            const uint4 v = tv[i];
            facc[0] += wt * bf2f(v.x & 0xffffu);
            facc[1] += wt * bf2f(v.x >> 16);
            facc[2] += wt * bf2f(v.y & 0xffffu);
            facc[3] += wt * bf2f(v.y >> 16);
            facc[4] += wt * bf2f(v.z & 0xffffu);
            facc[5] += wt * bf2f(v.z >> 16);
            facc[6] += wt * bf2f(v.w & 0xffffu);
            facc[7] += wt * bf2f(v.w >> 16);
        }
        {
            u32 wp[4];
#pragma unroll
            for (int i = 0; i < 4; ++i) wp[i] = pk2(facc[2 * i], facc[2 * i + 1]);
            *(uint4*)((char*)sX + p * 128 + ((q * 16) ^ sw)) =
                make_uint4(wp[0], wp[1], wp[2], wp[3]);
        }

        // view embedding -> X cols 32..63 (59..63 zero)
        if (q == 1 || q == 2) {
            const float d0 = vds[pg], d1 = vds[NPTS + pg], d2 = vds[2 * NPTS + pg];
            float e[16];
            if (q == 1) {
                e[0] = d0; e[1] = d1; e[2] = d2;
#pragma unroll
                for (int f = 0; f < 4; ++f) {
                    const float fr = (float)(1 << f);
                    e[3 + f * 3 + 0] = __sinf(d0 * fr);
                    e[3 + f * 3 + 1] = __sinf(d1 * fr);
                    e[3 + f * 3 + 2] = __sinf(d2 * fr);
                }
                e[15] = __cosf(d0);
            } else {
                e[0] = __cosf(d1); e[1] = __cosf(d2);
#pragma unroll
                for (int f = 1; f < 4; ++f) {
                    const float fr = (float)(1 << f);
                    e[2 + (f - 1) * 3 + 0] = __cosf(d0 * fr);
                    e[2 + (f - 1) * 3 + 1] = __cosf(d1 * fr);
                    e[2 + (f - 1) * 3 + 2] = __cosf(d2 * fr);
                }
#pragma unroll
                for (int i = 11; i < 16; ++i) e[i] = 0.f;
            }
            const int base = 64 + (q - 1) * 32;
#pragma unroll
            for (int g = 0; g < 2; ++g) {
                const u32 a0 = pk2(e[8 * g + 0], e[8 * g + 1]);
                const u32 a1 = pk2(e[8 * g + 2], e[8 * g + 3]);
                const u32 a2 = pk2(e[8 * g + 4], e[8 * g + 5]);
                const u32 a3 = pk2(e[8 * g + 6], e[8 * g + 7]);
                *(uint4*)((char*)sX + p * 128 + ((base + g * 16) ^ sw)) =
                    make_uint4(a0, a1, a2, a3);
            }
        }
    }

    // ---- prefetch: density GEMM2 b-frags kk=0,1 (in flight across barrier) ----
    bf16x8 b2dp[4];
#pragma unroll
    for (int nl = 0; nl < 2; ++nl)
#pragma unroll
        for (int kk = 0; kk < 2; ++kk) {
            const int n = wc * 32 + nl * 16 + l15;
            b2dp[nl * 2 + kk] = *(const bf16x8*)(gW2d + n * 128 + kk * 32 + l4 * 8);
        }
    __syncthreads();

    bf16x8 b1cp[4];   // color GEMM1 prefetch (filled during density GEMM1)

    // ================= DENSITY: GEMM1 (K=32), swapped =================
    {
        f32x4 acc[4][2];
        bf16x8 a[4];
#pragma unroll
        for (int mt = 0; mt < 4; ++mt) {
            const int m = mt * 16 + l15;
            a[mt] = *(const bf16x8*)((const char*)sX + m * 128 + (kb ^ ((m & 7) << 4)));
#pragma unroll
            for (int nl = 0; nl < 2; ++nl) acc[mt][nl] = FZ;
        }
#pragma unroll
        for (int nl = 0; nl < 2; ++nl)
#pragma unroll
            for (int mt = 0; mt < 4; ++mt)
                acc[mt][nl] = __builtin_amdgcn_mfma_f32_16x16x32_bf16(b1d[nl], a[mt], acc[mt][nl], 0, 0, 0);

        // prefetch color GEMM1 b-frags (covers G1d epilogue + barrier + G2d)
#pragma unroll
        for (int nl = 0; nl < 2; ++nl)
#pragma unroll
            for (int kk = 0; kk < 2; ++kk) {
                const int n = wc * 32 + nl * 16 + l15;
                b1cp[nl * 2 + kk] = *(const bf16x8*)(gW1c + n * 64 + kk * 32 + l4 * 8);
            }

        // epilogue: lane holds m=l15, n0..n0+3 -> one 8B store per fragment
#pragma unroll
        for (int nl = 0; nl < 2; ++nl) {
            const int n0 = wc * 32 + nl * 16 + l4 * 4;
            const f32x4 bv = *(const f32x4*)(gB1d + n0);
#pragma unroll
            for (int mt = 0; mt < 4; ++mt) {
                const int m = mt * 16 + l15;
                const float h0 = fmaxf(acc[mt][nl][0] + bv[0], 0.f);
                const float h1 = fmaxf(acc[mt][nl][1] + bv[1], 0.f);
                const float h2 = fmaxf(acc[mt][nl][2] + bv[2], 0.f);
                const float h3 = fmaxf(acc[mt][nl][3] + bv[3], 0.f);
                *(u32x2*)((char*)sH + m * 256 + ((n0 * 2) ^ ((m & 7) << 4))) =
                    u32x2{pk2(h0, h1), pk2(h2, h3)};
            }
        }
    }
    __syncthreads();

    bf16x8 b2cp[4];   // color GEMM2 kk=0,1 prefetch (filled during density GEMM2)

    // ================= DENSITY: GEMM2 (K=128), swapped + W3 dot =================
    {
        f32x4 bv[2], wv[2];
#pragma unroll
        for (int nl = 0; nl < 2; ++nl) {
            const int n0 = wc * 32 + nl * 16 + l4 * 4;
            bv[nl] = *(const f32x4*)(gB2d + n0);
            wv[nl] = *(const f32x4*)(gW3d + n0);
        }

        f32x4 acc[4][2];
#pragma unroll
        for (int mt = 0; mt < 4; ++mt)
#pragma unroll
            for (int nl = 0; nl < 2; ++nl) acc[mt][nl] = FZ;
#pragma unroll
        for (int kk = 0; kk < 4; ++kk) {
            bf16x8 a[4];
#pragma unroll
            for (int mt = 0; mt < 4; ++mt) {
                const int m = mt * 16 + l15;
                a[mt] = *(const bf16x8*)((const char*)sH + m * 256 + ((kk * 64 + kb) ^ ((m & 7) << 4)));
            }
#pragma unroll
            for (int nl = 0; nl < 2; ++nl) {
                const int n = wc * 32 + nl * 16 + l15;
                const bf16x8 b = (kk < 2) ? b2dp[nl * 2 + kk]
                                          : *(const bf16x8*)(gW2d + n * 128 + kk * 32 + l4 * 8);
#pragma unroll
                for (int mt = 0; mt < 4; ++mt)
                    acc[mt][nl] = __builtin_amdgcn_mfma_f32_16x16x32_bf16(b, a[mt], acc[mt][nl], 0, 0, 0);
            }
        }

        // prefetch color GEMM2 kk=0,1 (covers G2d epilogue + barrier + G1c)
#pragma unroll
        for (int nl = 0; nl < 2; ++nl)
#pragma unroll
            for (int kk = 0; kk < 2; ++kk) {
                const int n = wc * 32 + nl * 16 + l15;
                b2cp[nl * 2 + kk] = *(const bf16x8*)(gW2c + n * 128 + kk * 32 + l4 * 8);
            }

        // epilogue: in-register W3 dot, cross-l4 shfl reduce, l4==0 atomics
#pragma unroll
        for (int mt = 0; mt < 4; ++mt) {
            float s = 0.f;
#pragma unroll
            for (int nl = 0; nl < 2; ++nl)
#pragma unroll
                for (int r = 0; r < 4; ++r) {
                    const float h = fmaxf(acc[mt][nl][r] + bv[nl][r], 0.f);
                    s += h * wv[nl][r];
                }
            s += __shfl_xor(s, 16);
            s += __shfl_xor(s, 32);
            if (l4 == 0)
                atomicAdd(&sAcc[0 * 64 + mt * 16 + l15], s);
        }
    }
    __syncthreads();   // also guards sH overwrite below

    // ================= COLOR: GEMM1 (K=64), swapped =================
    {
        f32x4 acc[4][2];
#pragma unroll
        for (int mt = 0; mt < 4; ++mt)
#pragma unroll
            for (int nl = 0; nl < 2; ++nl) acc[mt][nl] = FZ;
#pragma unroll
        for (int kk = 0; kk < 2; ++kk) {
            bf16x8 a[4];
#pragma unroll
            for (int mt = 0; mt < 4; ++mt) {
                const int m = mt * 16 + l15;
                a[mt] = *(const bf16x8*)((const char*)sX + m * 128 + ((kk * 64 + kb) ^ ((m & 7) << 4)));
            }
#pragma unroll
            for (int nl = 0; nl < 2; ++nl)
#pragma unroll
                for (int mt = 0; mt < 4; ++mt)
                    acc[mt][nl] = __builtin_amdgcn_mfma_f32_16x16x32_bf16(b1cp[nl * 2 + kk], a[mt], acc[mt][nl], 0, 0, 0);
        }
#pragma unroll
        for (int nl = 0; nl < 2; ++nl) {
            const int n0 = wc * 32 + nl * 16 + l4 * 4;
            const f32x4 bv = *(const f32x4*)(gB1c + n0);
#pragma unroll
            for (int mt = 0; mt < 4; ++mt) {
                const int m = mt * 16 + l15;
                const float h0 = fmaxf(acc[mt][nl][0] + bv[0], 0.f);
                const float h1 = fmaxf(acc[mt][nl][1] + bv[1], 0.f);
                const float h2 = fmaxf(acc[mt][nl][2] + bv[2], 0.f);
                const float h3 = fmaxf(acc[mt][nl][3] + bv[3], 0.f);
                *(u32x2*)((char*)sH + m * 256 + ((n0 * 2) ^ ((m & 7) << 4))) =
                    u32x2{pk2(h0, h1), pk2(h2, h3)};
            }
        }
    }
    __syncthreads();

    // ================= COLOR: GEMM2 (K=128), swapped + W3 dots =================
    {
        f32x4 bv[2], w0v[2], w1v[2], w2v[2];
#pragma unroll
        for (int nl = 0; nl < 2; ++nl) {
            const int n0 = wc * 32 + nl * 16 + l4 * 4;
            bv[nl]  = *(const f32x4*)(gB2c + n0);
            w0v[nl] = *(const f32x4*)(gW3ct + 0 * 128 + n0);
            w1v[nl] = *(const f32x4*)(gW3ct + 1 * 128 + n0);
            w2v[nl] = *(const f32x4*)(gW3ct + 2 * 128 + n0);
        }

        f32x4 acc[4][2];
#pragma unroll
        for (int mt = 0; mt < 4; ++mt)
#pragma unroll
            for (int nl = 0; nl < 2; ++nl) acc[mt][nl] = FZ;
#pragma unroll
        for (int kk = 0; kk < 4; ++kk) {
            bf16x8 a[4];
#pragma unroll
            for (int mt = 0; mt < 4; ++mt) {
                const int m = mt * 16 + l15;
                a[mt] = *(const bf16x8*)((const char*)sH + m * 256 + ((kk * 64 + kb) ^ ((m & 7) << 4)));
            }
#pragma unroll
            for (int nl = 0; nl < 2; ++nl) {
                const int n = wc * 32 + nl * 16 + l15;
                const bf16x8 b = (kk < 2) ? b2cp[nl * 2 + kk]
                                          : *(const bf16x8*)(gW2c + n * 128 + kk * 32 + l4 * 8);
#pragma unroll
                for (int mt = 0; mt < 4; ++mt)
                    acc[mt][nl] = __builtin_amdgcn_mfma_f32_16x16x32_bf16(b, a[mt], acc[mt][nl], 0, 0, 0);
            }
        }

#pragma unroll
        for (int mt = 0; mt < 4; ++mt) {
            float s0 = 0.f, s1 = 0.f, s2 = 0.f;
#pragma unroll
            for (int nl = 0; nl < 2; ++nl)
#pragma unroll
                for (int r = 0; r < 4; ++r) {
                    const float h = fmaxf(acc[mt][nl][r] + bv[nl][r], 0.f);
                    s0 += h * w0v[nl][r];
                    s1 += h * w1v[nl][r];
                    s2 += h * w2v[nl][r];
                }
            s0 += __shfl_xor(s0, 16); s0 += __shfl_xor(s0, 32);
            s1 += __shfl_xor(s1, 16); s1 += __shfl_xor(s1, 32);
            s2 += __shfl_xor(s2, 16); s2 += __shfl_xor(s2, 32);
            if (l4 == 0) {
                atomicAdd(&sAcc[1 * 64 + mt * 16 + l15], s0);
                atomicAdd(&sAcc[2 * 64 + mt * 16 + l15], s1);
                atomicAdd(&sAcc[3 * 64 + mt * 16 + l15], s2);
            }
        }
    }
    __syncthreads();

    // ---- write out (1,4,N): ch0 = density, ch1..3 = color ----
    {
        const int ch = t >> 6, row = t & 63;
        const float bias = (ch == 0) ? gB3d[0] : gB3c[ch - 1];
        out[(size_t)ch * NPTS + pbase + row] = sAcc[ch * 64 + row] + bias;
    }
}

// ---------------------------------------------------------------------------
extern "C" void kernel_launch(void* const* d_in, const int* in_sizes, int n_in,
                              void* d_out, int out_size, void* d_ws, size_t ws_size,
                              hipStream_t stream) {
    (void)in_sizes; (void)n_in; (void)out_size; (void)ws_size;
    const float* pts = (const float*)d_in[0];
    const float* vds = (const float*)d_in[1];
    const float* tp  = (const float*)d_in[2];
    const float* dW1 = (const float*)d_in[3];
    const float* dB1 = (const float*)d_in[4];
    const float* dW2 = (const float*)d_in[5];
    const float* dB2 = (const float*)d_in[6];
    const float* dW3 = (const float*)d_in[7];
    const float* dB3 = (const float*)d_in[8];
    const float* cW1 = (const float*)d_in[9];
    const float* cB1 = (const float*)d_in[10];
    const float* cW2 = (const float*)d_in[11];
    const float* cB2 = (const float*)d_in[12];
    const float* cW3 = (const float*)d_in[13];
    const float* cB3 = (const float*)d_in[14];
    float* out = (float*)d_out;

    u16* planes_t = (u16*)d_ws;                          // 12 MB
    u16* w1d = planes_t + (size_t)3 * RES * RES * PD;
    u16* w1c = w1d + 128 * 32;
    u16* w2d = w1c + 128 * 64;
    u16* w2c = w2d + 128 * 128;
    float* w3ct = (float*)(w2c + 128 * 128);             // 3*128 fp32

    k_transpose_planes<<<3 * RES, 256, 0, stream>>>(tp, planes_t);
    k_prep_weights<<<64, 256, 0, stream>>>(dW1, dW2, cW1, cW2, cW3,
                                           w1d, w1c, w2d, w2c, w3ct);
    k_fused<<<NPTS / 64, 256, 0, stream>>>(pts, vds, planes_t,
                                           w1d, w1c, w2d, w2c,
                                           dB1, dB2, dW3, dB3,
                                           cB1, cB2, w3ct, cB3,
                                           out);
}

// Round 20
// 85.593 us; speedup vs baseline: 1.2720x; 1.0403x over previous
//
#include <hip/hip_runtime.h>

#define NPTS 262144
#define RES  256
#define PD   32

typedef unsigned short u16;
typedef unsigned int   u32;

typedef __bf16 bf16x8 __attribute__((ext_vector_type(8)));
typedef float  f32x4  __attribute__((ext_vector_type(4)));
typedef u32    u32x2  __attribute__((ext_vector_type(2)));

__device__ __forceinline__ u16 f2bf(float f) {
    return __builtin_bit_cast(u16, (__bf16)f);
}
__device__ __forceinline__ float bf2f(u32 u) {
    return __builtin_bit_cast(float, (u32)(u << 16));
}
__device__ __forceinline__ u32 pk2(float a, float b) {
    return (u32)f2bf(a) | ((u32)f2bf(b) << 16);
}

// ---------------------------------------------------------------------------
// Prep 1: triplanes (3,32,256,256) fp32 -> (3,256,256,32) bf16
// ---------------------------------------------------------------------------
__global__ void k_transpose_planes(const float* __restrict__ tp, u16* __restrict__ dst) {
    const int b  = blockIdx.x;          // 0..767
    const int pl = b >> 8, y = b & 255;
    const int x  = threadIdx.x;         // 0..255
    const float* src = tp + ((size_t)pl * PD * RES + y) * RES + x;
    u32 w[16];
#pragma unroll
    for (int c = 0; c < 16; ++c) {
        const float v0 = src[(size_t)(2 * c)     * (RES * RES)];
        const float v1 = src[(size_t)(2 * c + 1) * (RES * RES)];
        w[c] = (u32)f2bf(v0) | ((u32)f2bf(v1) << 16);
    }
    uint4* d = (uint4*)(dst + (size_t)((pl * RES + y) * RES + x) * PD);
    d[0] = make_uint4(w[0],  w[1],  w[2],  w[3]);
    d[1] = make_uint4(w[4],  w[5],  w[6],  w[7]);
    d[2] = make_uint4(w[8],  w[9],  w[10], w[11]);
    d[3] = make_uint4(w[12], w[13], w[14], w[15]);
}

// ---------------------------------------------------------------------------
// Prep 2: weights -> bf16 (N x K row-major) + W3c transpose (fp32 3x128).
// ---------------------------------------------------------------------------
__global__ void k_prep_weights(const float* __restrict__ dW1, const float* __restrict__ dW2,
                               const float* __restrict__ cW1, const float* __restrict__ cW2,
                               const float* __restrict__ cW3,
                               u16* __restrict__ w1d, u16* __restrict__ w1c,
                               u16* __restrict__ w2d, u16* __restrict__ w2c,
                               float* __restrict__ w3ct) {
    const int tid = blockIdx.x * 256 + threadIdx.x;   // 0..16383
    if (tid < 128 * 32) { const int n = tid >> 5, k = tid & 31; w1d[tid] = f2bf(dW1[k * 128 + n]); }
    if (tid < 128 * 64) { const int n = tid >> 6, k = tid & 63; w1c[tid] = f2bf(k < 59 ? cW1[k * 128 + n] : 0.f); }
    if (tid < 3 * 128) { w3ct[tid] = cW3[(tid & 127) * 3 + (tid >> 7)]; }
    { const int n = tid >> 7, k = tid & 127;
      w2d[tid] = f2bf(dW2[k * 128 + n]);
      w2c[tid] = f2bf(cW2[k * 128 + n]); }
}

// ---------------------------------------------------------------------------
// Fused head kernel. 4096 blocks x 256 threads, TILE = 64 points/block.
// r16/r19 BEST CONFIG + T5 s_setprio(1) around the four MFMA clusters:
// blocks on a CU sit at staggered phases (gather vs GEMM), so priority-
// boosting MFMA-phase waves lets them run while gather waves wait anyway.
// Session ledger of falsified alternatives (do not retry):
//  - launch_bounds (512,6)/(256,5): allocator clamp -> 254MB spill traffic
//  - 42KB-LDS phase merge (r9), zero-barrier per-wave (r4), split kernels (r7)
//  - dropping b2* prefetches (r14), no-mask sampling (r8/r11 WRONG),
//    packed FMA / load hoists (r16/r17 null), cross-tile prefetch (r18 -20us)
// ---------------------------------------------------------------------------
__global__ __launch_bounds__(256) void k_fused(
    const float* __restrict__ pts, const float* __restrict__ vds,
    const u16* __restrict__ planes,
    const u16* __restrict__ gW1d, const u16* __restrict__ gW1c,
    const u16* __restrict__ gW2d, const u16* __restrict__ gW2c,
    const float* __restrict__ gB1d, const float* __restrict__ gB2d,
    const float* __restrict__ gW3d, const float* __restrict__ gB3d,
    const float* __restrict__ gB1c, const float* __restrict__ gB2c,
    const float* __restrict__ gW3ct, const float* __restrict__ gB3c,
    float* __restrict__ out) {
    __shared__ __align__(16) u16 sX[64 * 64];       //  8 KB, 128B rows, swizzled
    __shared__ __align__(16) u16 sH[64 * 128];      // 16 KB, 256B rows, swizzled
    __shared__ float sAcc[4 * 64];                  //  1 KB

    const int t    = threadIdx.x;
    const int lane = t & 63;
    const int wc   = t >> 6;          // wave = n-column group (0..3)
    const int l15  = lane & 15;
    const int l4   = lane >> 4;
    const int kb   = l4 * 16;         // byte offset of lane's k-slice in a 64B k-step
    const int pbase = blockIdx.x * 64;
    const f32x4 FZ = {0.f, 0.f, 0.f, 0.f};

    sAcc[t] = 0.f;

    // ---- prefetch: density GEMM1 b-frags (in flight during sampling) ----
    bf16x8 b1d[2];
#pragma unroll
    for (int nl = 0; nl < 2; ++nl) {
        const int n = wc * 32 + nl * 16 + l15;
        b1d[nl] = *(const bf16x8*)(gW1d + n * 32 + l4 * 8);
    }

    // ---- phase 1: bilinear triplane sampling + view embedding -> sX ----
    {
        const int p = t >> 2, q = t & 3;       // 4 threads/point
        const int pg = pbase + p;
        const int sw = (p & 7) << 4;
        const float pu = pts[pg], pv = pts[NPTS + pg], pw = pts[2 * NPTS + pg];

        uint4 tv[12];
        float wts[12];

        // pass 1: weights + issue all 12 loads (r6-verbatim masks/clamps)
#pragma unroll
        for (int pl = 0; pl < 3; ++pl) {
            const float gx = (pl == 0) ? pv : pu;
            const float gy = (pl == 2) ? pv : pw;
            const float px = (gx + 1.f) * 127.5f;
            const float py = (gy + 1.f) * 127.5f;
            const float x0 = floorf(px), y0 = floorf(py);
            const float fx = px - x0, fy = py - y0;
            const int ix = (int)x0, iy = (int)y0;
            const u16* pb = planes + (size_t)pl * (RES * RES * PD) + q * 8;
#pragma unroll
            for (int dy = 0; dy < 2; ++dy) {
#pragma unroll
                for (int dx = 0; dx < 2; ++dx) {
                    const int i = pl * 4 + dy * 2 + dx;
                    const int xi = ix + dx, yi = iy + dy;
                    float wt = (dx ? fx : 1.f - fx) * (dy ? fy : 1.f - fy);
                    if (xi < 0 || xi > RES - 1 || yi < 0 || yi > RES - 1) wt = 0.f;
                    const int xc = xi < 0 ? 0 : (xi > RES - 1 ? RES - 1 : xi);
                    const int yc = yi < 0 ? 0 : (yi > RES - 1 ? RES - 1 : yi);
                    wts[i] = wt;
                    tv[i] = *(const uint4*)(pb + ((size_t)(yc * RES + xc) << 5));
                }
            }
        }

        // pass 2: consume in identical order
        float facc[8] = {0.f, 0.f, 0.f, 0.f, 0.f, 0.f, 0.f, 0.f};
#pragma unroll
        for (int i = 0; i < 12; ++i) {
            const float wt = wts[i];
            const uint4 v = tv[i];
            facc[0] += wt * bf2f(v.x & 0xffffu);
            facc[1] += wt * bf2f(v.x >> 16);
            facc[2] += wt * bf2f(v.y & 0xffffu);
            facc[3] += wt * bf2f(v.y >> 16);
            facc[4] += wt * bf2f(v.z & 0xffffu);
            facc[5] += wt * bf2f(v.z >> 16);
            facc[6] += wt * bf2f(v.w & 0xffffu);
            facc[7] += wt * bf2f(v.w >> 16);
        }
        {
            u32 wp[4];
#pragma unroll
            for (int i = 0; i < 4; ++i) wp[i] = pk2(facc[2 * i], facc[2 * i + 1]);
            *(uint4*)((char*)sX + p * 128 + ((q * 16) ^ sw)) =
                make_uint4(wp[0], wp[1], wp[2], wp[3]);
        }

        // view embedding -> X cols 32..63 (59..63 zero)
        if (q == 1 || q == 2) {
            const float d0 = vds[pg], d1 = vds[NPTS + pg], d2 = vds[2 * NPTS + pg];
            float e[16];
            if (q == 1) {
                e[0] = d0; e[1] = d1; e[2] = d2;
#pragma unroll
                for (int f = 0; f < 4; ++f) {
                    const float fr = (float)(1 << f);
                    e[3 + f * 3 + 0] = __sinf(d0 * fr);
                    e[3 + f * 3 + 1] = __sinf(d1 * fr);
                    e[3 + f * 3 + 2] = __sinf(d2 * fr);
                }
                e[15] = __cosf(d0);
            } else {
                e[0] = __cosf(d1); e[1] = __cosf(d2);
#pragma unroll
                for (int f = 1; f < 4; ++f) {
                    const float fr = (float)(1 << f);
                    e[2 + (f - 1) * 3 + 0] = __cosf(d0 * fr);
                    e[2 + (f - 1) * 3 + 1] = __cosf(d1 * fr);
                    e[2 + (f - 1) * 3 + 2] = __cosf(d2 * fr);
                }
#pragma unroll
                for (int i = 11; i < 16; ++i) e[i] = 0.f;
            }
            const int base = 64 + (q - 1) * 32;
#pragma unroll
            for (int g = 0; g < 2; ++g) {
                const u32 a0 = pk2(e[8 * g + 0], e[8 * g + 1]);
                const u32 a1 = pk2(e[8 * g + 2], e[8 * g + 3]);
                const u32 a2 = pk2(e[8 * g + 4], e[8 * g + 5]);
                const u32 a3 = pk2(e[8 * g + 6], e[8 * g + 7]);
                *(uint4*)((char*)sX + p * 128 + ((base + g * 16) ^ sw)) =
                    make_uint4(a0, a1, a2, a3);
            }
        }
    }

    // ---- prefetch: density GEMM2 b-frags kk=0,1 (in flight across barrier) ----
    bf16x8 b2dp[4];
#pragma unroll
    for (int nl = 0; nl < 2; ++nl)
#pragma unroll
        for (int kk = 0; kk < 2; ++kk) {
            const int n = wc * 32 + nl * 16 + l15;
            b2dp[nl * 2 + kk] = *(const bf16x8*)(gW2d + n * 128 + kk * 32 + l4 * 8);
        }
    __syncthreads();

    bf16x8 b1cp[4];   // color GEMM1 prefetch (filled during density GEMM1)

    // ================= DENSITY: GEMM1 (K=32), swapped =================
    {
        f32x4 acc[4][2];
        bf16x8 a[4];
#pragma unroll
        for (int mt = 0; mt < 4; ++mt) {
            const int m = mt * 16 + l15;
            a[mt] = *(const bf16x8*)((const char*)sX + m * 128 + (kb ^ ((m & 7) << 4)));
#pragma unroll
            for (int nl = 0; nl < 2; ++nl) acc[mt][nl] = FZ;
        }
        __builtin_amdgcn_s_setprio(1);
#pragma unroll
        for (int nl = 0; nl < 2; ++nl)
#pragma unroll
            for (int mt = 0; mt < 4; ++mt)
                acc[mt][nl] = __builtin_amdgcn_mfma_f32_16x16x32_bf16(b1d[nl], a[mt], acc[mt][nl], 0, 0, 0);
        __builtin_amdgcn_s_setprio(0);

        // prefetch color GEMM1 b-frags (covers G1d epilogue + barrier + G2d)
#pragma unroll
        for (int nl = 0; nl < 2; ++nl)
#pragma unroll
            for (int kk = 0; kk < 2; ++kk) {
                const int n = wc * 32 + nl * 16 + l15;
                b1cp[nl * 2 + kk] = *(const bf16x8*)(gW1c + n * 64 + kk * 32 + l4 * 8);
            }

        // epilogue: lane holds m=l15, n0..n0+3 -> one 8B store per fragment
#pragma unroll
        for (int nl = 0; nl < 2; ++nl) {
            const int n0 = wc * 32 + nl * 16 + l4 * 4;
            const f32x4 bv = *(const f32x4*)(gB1d + n0);
#pragma unroll
            for (int mt = 0; mt < 4; ++mt) {
                const int m = mt * 16 + l15;
                const float h0 = fmaxf(acc[mt][nl][0] + bv[0], 0.f);
                const float h1 = fmaxf(acc[mt][nl][1] + bv[1], 0.f);
                const float h2 = fmaxf(acc[mt][nl][2] + bv[2], 0.f);
                const float h3 = fmaxf(acc[mt][nl][3] + bv[3], 0.f);
                *(u32x2*)((char*)sH + m * 256 + ((n0 * 2) ^ ((m & 7) << 4))) =
                    u32x2{pk2(h0, h1), pk2(h2, h3)};
            }
        }
    }
    __syncthreads();

    bf16x8 b2cp[4];   // color GEMM2 kk=0,1 prefetch (filled during density GEMM2)

    // ================= DENSITY: GEMM2 (K=128), swapped + W3 dot =================
    {
        f32x4 bv[2], wv[2];
#pragma unroll
        for (int nl = 0; nl < 2; ++nl) {
            const int n0 = wc * 32 + nl * 16 + l4 * 4;
            bv[nl] = *(const f32x4*)(gB2d + n0);
            wv[nl] = *(const f32x4*)(gW3d + n0);
        }

        f32x4 acc[4][2];
#pragma unroll
        for (int mt = 0; mt < 4; ++mt)
#pragma unroll
            for (int nl = 0; nl < 2; ++nl) acc[mt][nl] = FZ;
        __builtin_amdgcn_s_setprio(1);
#pragma unroll
        for (int kk = 0; kk < 4; ++kk) {
            bf16x8 a[4];
#pragma unroll
            for (int mt = 0; mt < 4; ++mt) {
                const int m = mt * 16 + l15;
                a[mt] = *(const bf16x8*)((const char*)sH + m * 256 + ((kk * 64 + kb) ^ ((m & 7) << 4)));
            }
#pragma unroll
            for (int nl = 0; nl < 2; ++nl) {
                const int n = wc * 32 + nl * 16 + l15;
                const bf16x8 b = (kk < 2) ? b2dp[nl * 2 + kk]
                                          : *(const bf16x8*)(gW2d + n * 128 + kk * 32 + l4 * 8);
#pragma unroll
                for (int mt = 0; mt < 4; ++mt)
                    acc[mt][nl] = __builtin_amdgcn_mfma_f32_16x16x32_bf16(b, a[mt], acc[mt][nl], 0, 0, 0);
            }
        }
        __builtin_amdgcn_s_setprio(0);

        // prefetch color GEMM2 kk=0,1 (covers G2d epilogue + barrier + G1c)
#pragma unroll
        for (int nl = 0; nl < 2; ++nl)
#pragma unroll
            for (int kk = 0; kk < 2; ++kk) {
                const int n = wc * 32 + nl * 16 + l15;
                b2cp[nl * 2 + kk] = *(const bf16x8*)(gW2c + n * 128 + kk * 32 + l4 * 8);
            }

        // epilogue: in-register W3 dot, cross-l4 shfl reduce, l4==0 atomics
#pragma unroll
        for (int mt = 0; mt < 4; ++mt) {
            float s = 0.f;
#pragma unroll
            for (int nl = 0; nl < 2; ++nl)
#pragma unroll
                for (int r = 0; r < 4; ++r) {
                    const float h = fmaxf(acc[mt][nl][r] + bv[nl][r], 0.f);
                    s += h * wv[nl][r];
                }
            s += __shfl_xor(s, 16);
            s += __shfl_xor(s, 32);
            if (l4 == 0)
                atomicAdd(&sAcc[0 * 64 + mt * 16 + l15], s);
        }
    }
    __syncthreads();   // also guards sH overwrite below

    // ================= COLOR: GEMM1 (K=64), swapped =================
    {
        f32x4 acc[4][2];
#pragma unroll
        for (int mt = 0; mt < 4; ++mt)
#pragma unroll
            for (int nl = 0; nl < 2; ++nl) acc[mt][nl] = FZ;
        __builtin_amdgcn_s_setprio(1);
#pragma unroll
        for (int kk = 0; kk < 2; ++kk) {
            bf16x8 a[4];
#pragma unroll
            for (int mt = 0; mt < 4; ++mt) {
                const int m = mt * 16 + l15;
                a[mt] = *(const bf16x8*)((const char*)sX + m * 128 + ((kk * 64 + kb) ^ ((m & 7) << 4)));
            }
#pragma unroll
            for (int nl = 0; nl < 2; ++nl)
#pragma unroll
                for (int mt = 0; mt < 4; ++mt)
                    acc[mt][nl] = __builtin_amdgcn_mfma_f32_16x16x32_bf16(b1cp[nl * 2 + kk], a[mt], acc[mt][nl], 0, 0, 0);
        }
        __builtin_amdgcn_s_setprio(0);
#pragma unroll
        for (int nl = 0; nl < 2; ++nl) {
            const int n0 = wc * 32 + nl * 16 + l4 * 4;
            const f32x4 bv = *(const f32x4*)(gB1c + n0);
#pragma unroll
            for (int mt = 0; mt < 4; ++mt) {
                const int m = mt * 16 + l15;
                const float h0 = fmaxf(acc[mt][nl][0] + bv[0], 0.f);
                const float h1 = fmaxf(acc[mt][nl][1] + bv[1], 0.f);
                const float h2 = fmaxf(acc[mt][nl][2] + bv[2], 0.f);
                const float h3 = fmaxf(acc[mt][nl][3] + bv[3], 0.f);
                *(u32x2*)((char*)sH + m * 256 + ((n0 * 2) ^ ((m & 7) << 4))) =
                    u32x2{pk2(h0, h1), pk2(h2, h3)};
            }
        }
    }
    __syncthreads();

    // ================= COLOR: GEMM2 (K=128), swapped + W3 dots =================
    {
        f32x4 bv[2], w0v[2], w1v[2], w2v[2];
#pragma unroll
        for (int nl = 0; nl < 2; ++nl) {
            const int n0 = wc * 32 + nl * 16 + l4 * 4;
            bv[nl]  = *(const f32x4*)(gB2c + n0);
            w0v[nl] = *(const f32x4*)(gW3ct + 0 * 128 + n0);
            w1v[nl] = *(const f32x4*)(gW3ct + 1 * 128 + n0);
            w2v[nl] = *(const f32x4*)(gW3ct + 2 * 128 + n0);
        }

        f32x4 acc[4][2];
#pragma unroll
        for (int mt = 0; mt < 4; ++mt)
#pragma unroll
            for (int nl = 0; nl < 2; ++nl) acc[mt][nl] = FZ;
        __builtin_amdgcn_s_setprio(1);
#pragma unroll
        for (int kk = 0; kk < 4; ++kk) {
            bf16x8 a[4];
#pragma unroll
            for (int mt = 0; mt < 4; ++mt) {
                const int m = mt * 16 + l15;
                a[mt] = *(const bf16x8*)((const char*)sH + m * 256 + ((kk * 64 + kb) ^ ((m & 7) << 4)));
            }
#pragma unroll
            for (int nl = 0; nl < 2; ++nl) {
                const int n = wc * 32 + nl * 16 + l15;
                const bf16x8 b = (kk < 2) ? b2cp[nl * 2 + kk]
                                          : *(const bf16x8*)(gW2c + n * 128 + kk * 32 + l4 * 8);
#pragma unroll
                for (int mt = 0; mt < 4; ++mt)
                    acc[mt][nl] = __builtin_amdgcn_mfma_f32_16x16x32_bf16(b, a[mt], acc[mt][nl], 0, 0, 0);
            }
        }
        __builtin_amdgcn_s_setprio(0);

#pragma unroll
        for (int mt = 0; mt < 4; ++mt) {
            float s0 = 0.f, s1 = 0.f, s2 = 0.f;
#pragma unroll
            for (int nl = 0; nl < 2; ++nl)
#pragma unroll
                for (int r = 0; r < 4; ++r) {
                    const float h = fmaxf(acc[mt][nl][r] + bv[nl][r], 0.f);
                    s0 += h * w0v[nl][r];
                    s1 += h * w1v[nl][r];
                    s2 += h * w2v[nl][r];
                }
            s0 += __shfl_xor(s0, 16); s0 += __shfl_xor(s0, 32);
            s1 += __shfl_xor(s1, 16); s1 += __shfl_xor(s1, 32);
            s2 += __shfl_xor(s2, 16); s2 += __shfl_xor(s2, 32);
            if (l4 == 0) {
                atomicAdd(&sAcc[1 * 64 + mt * 16 + l15], s0);
                atomicAdd(&sAcc[2 * 64 + mt * 16 + l15], s1);
                atomicAdd(&sAcc[3 * 64 + mt * 16 + l15], s2);
            }
        }
    }
    __syncthreads();

    // ---- write out (1,4,N): ch0 = density, ch1..3 = color ----
    {
        const int ch = t >> 6, row = t & 63;
        const float bias = (ch == 0) ? gB3d[0] : gB3c[ch - 1];
        out[(size_t)ch * NPTS + pbase + row] = sAcc[ch * 64 + row] + bias;
    }
}

// ---------------------------------------------------------------------------
extern "C" void kernel_launch(void* const* d_in, const int* in_sizes, int n_in,
                              void* d_out, int out_size, void* d_ws, size_t ws_size,
                              hipStream_t stream) {
    (void)in_sizes; (void)n_in; (void)out_size; (void)ws_size;
    const float* pts = (const float*)d_in[0];
    const float* vds = (const float*)d_in[1];
    const float* tp  = (const float*)d_in[2];
    const float* dW1 = (const float*)d_in[3];
    const float* dB1 = (const float*)d_in[4];
    const float* dW2 = (const float*)d_in[5];
    const float* dB2 = (const float*)d_in[6];
    const float* dW3 = (const float*)d_in[7];
    const float* dB3 = (const float*)d_in[8];
    const float* cW1 = (const float*)d_in[9];
    const float* cB1 = (const float*)d_in[10];
    const float* cW2 = (const float*)d_in[11];
    const float* cB2 = (const float*)d_in[12];
    const float* cW3 = (const float*)d_in[13];
    const float* cB3 = (const float*)d_in[14];
    float* out = (float*)d_out;

    u16* planes_t = (u16*)d_ws;                          // 12 MB
    u16* w1d = planes_t + (size_t)3 * RES * RES * PD;
    u16* w1c = w1d + 128 * 32;
    u16* w2d = w1c + 128 * 64;
    u16* w2c = w2d + 128 * 128;
    float* w3ct = (float*)(w2c + 128 * 128);             // 3*128 fp32

    k_transpose_planes<<<3 * RES, 256, 0, stream>>>(tp, planes_t);
    k_prep_weights<<<64, 256, 0, stream>>>(dW1, dW2, cW1, cW2, cW3,
                                           w1d, w1c, w2d, w2c, w3ct);
    k_fused<<<NPTS / 64, 256, 0, stream>>>(pts, vds, planes_t,
                                           w1d, w1c, w2d, w2c,
                                           dB1, dB2, dW3, dB3,
                                           cB1, cB2, w3ct, cB3,
                                           out);
}